// Round 3
// baseline (289.409 us; speedup 1.0000x reference)
//
#include <hip/hip_runtime.h>
#include <hip/hip_bf16.h>

#define B_ 2
#define T_ 2048
#define D_ 2048
#define NH_ 16
#define NKV_ 4
#define HD_ 128

using bf16 = __bf16;
using bf16x8 = __attribute__((ext_vector_type(8))) __bf16;
using bf16x4 = __attribute__((ext_vector_type(4))) __bf16;
using f32x4 = __attribute__((ext_vector_type(4))) float;

__device__ __forceinline__ void gld_lds16(bf16* lds, const bf16* g) {
  __builtin_amdgcn_global_load_lds(
      (const __attribute__((address_space(1))) void*)g,
      (__attribute__((address_space(3))) void*)lds, 16, 0, 0);
}

// ---------------- f32 -> bf16 convert ----------------
__global__ __launch_bounds__(256) void cvt_bf16(const float* __restrict__ in,
                                                bf16* __restrict__ out, int n4) {
  int i = blockIdx.x * 256 + threadIdx.x;
  if (i >= n4) return;
  float4 v = ((const float4*)in)[i];
  bf16x4 o;
  o[0] = (bf16)v.x; o[1] = (bf16)v.y; o[2] = (bf16)v.z; o[3] = (bf16)v.w;
  ((bf16x4*)out)[i] = o;
}

// ---------------- GEMM: C[M,N] = A[M,K] * Bt[N,K]^T ----------------
// 128x128 tile, BK=32, 256 threads (4 waves, 2x2), mfma 16x16x32 bf16.
// XCD-aware bijective block swizzle (grid size must be %8==0 — it is).
template<typename OutT>
__global__ __launch_bounds__(256) void gemm_bt(const bf16* __restrict__ A,
                                               const bf16* __restrict__ Bt,
                                               OutT* __restrict__ C,
                                               int M, int N, int K) {
  __shared__ bf16 As[128 * 32];
  __shared__ bf16 Bs[128 * 32];
  const int tid = threadIdx.x;
  const int wid = tid >> 6;
  const int lane = tid & 63;
  const int g = lane >> 4, r = lane & 15;
  const int wm = wid >> 1, wn = wid & 1;
  const int gx = gridDim.x;
  const int nwg = gx * gridDim.y;
  const int flat = blockIdx.y * gx + blockIdx.x;
  const int swz = (flat & 7) * (nwg >> 3) + (flat >> 3);
  const long bm = (long)(swz / gx) * 128, bn = (long)(swz % gx) * 128;
  f32x4 acc[4][4] = {};

  for (int k0 = 0; k0 < K; k0 += 32) {
    __syncthreads();
    for (int c = 0; c < 2; ++c) {
      int ch = wid * 2 + c;
      int row = ch * 16 + (lane >> 2);
      int col = (lane & 3) * 8;
      gld_lds16(As + ch * 512, A + (bm + row) * K + k0 + col);
      gld_lds16(Bs + ch * 512, Bt + (bn + row) * K + k0 + col);
    }
    asm volatile("s_waitcnt vmcnt(0)" ::: "memory");
    __syncthreads();
    bf16x8 af[4], bfr[4];
    for (int m = 0; m < 4; ++m)
      af[m] = *(const bf16x8*)(As + (wm * 64 + m * 16 + r) * 32 + g * 8);
    for (int n = 0; n < 4; ++n)
      bfr[n] = *(const bf16x8*)(Bs + (wn * 64 + n * 16 + r) * 32 + g * 8);
    for (int m = 0; m < 4; ++m)
      for (int n = 0; n < 4; ++n)
        acc[m][n] = __builtin_amdgcn_mfma_f32_16x16x32_bf16(af[m], bfr[n], acc[m][n], 0, 0, 0);
  }

  for (int m = 0; m < 4; ++m)
    for (int n = 0; n < 4; ++n)
      for (int e = 0; e < 4; ++e) {
        long row = bm + wm * 64 + m * 16 + g * 4 + e;
        long col = bn + wn * 64 + n * 16 + r;
        C[row * N + col] = (OutT)acc[m][n][e];
      }
}

// ---------------- fused RMSNorm + RoPE (reads from fused QKV buffer) ----------------
template<int IS_K>
__global__ __launch_bounds__(256) void norm_rope(const bf16* __restrict__ qkv,
                                                 const float* __restrict__ w,
                                                 bf16* __restrict__ out) {
  const int lane = threadIdx.x & 63;
  const int rloc = threadIdx.x >> 6;
  const int NHH = IS_K ? NKV_ : NH_;
  const int COFF = IS_K ? 2048 : 0;
  const long rid = (long)blockIdx.x * 4 + rloc;
  const int h = (int)(rid % NHH);
  const long bt = rid / NHH;  // b*T + t
  const int t = (int)(bt % T_);
  const bf16* src = qkv + bt * 3072 + COFF + h * HD_;
  float v0 = (float)src[lane];
  float v1 = (float)src[lane + 64];
  float ss = v0 * v0 + v1 * v1;
  for (int o = 1; o < 64; o <<= 1) ss += __shfl_xor(ss, o, 64);
  float inv = rsqrtf(ss * (1.f / HD_) + 1e-6f);
  float n0 = v0 * inv * w[lane];
  float n1 = v1 * inv * w[lane + 64];
  float ang = (float)t * exp2f((float)lane * (-13.287712379549449f / 64.f));
  float sv, cv;
  __sincosf(ang, &sv, &cv);
  float o0 = n0 * cv - n1 * sv;
  float o1 = n1 * cv + n0 * sv;
  bf16* dst;
  if (IS_K) {
    long b = bt / T_;
    dst = out + ((b * NKV_ + h) * (long)T_ + t) * HD_;  // [B][NKV][T][HD]
  } else {
    dst = out + (bt * NH_ + h) * HD_;  // [B*T][NH*HD]
  }
  dst[lane] = (bf16)o0;
  dst[lane + 64] = (bf16)o1;
}

// ---------------- V transpose: QKV[.., 2560+kv*128+d] -> [B][NKV][HD][T] ----------------
__global__ __launch_bounds__(256) void vpack(const bf16* __restrict__ qkv,
                                             bf16* __restrict__ Vt) {
  __shared__ float tile[64][65];
  const int tt = blockIdx.x;
  const int dd = blockIdx.y & 1;
  const int bkv = blockIdx.y >> 1;
  const long b = bkv >> 2;
  const int kv = bkv & 3;
  const int t0 = tt * 64, d0 = dd * 64;
  for (int i = 0; i < 2; ++i) {
    int row = i * 32 + (threadIdx.x >> 3);
    int c8 = (threadIdx.x & 7) * 8;
    bf16x8 v = *(const bf16x8*)&qkv[(b * T_ + t0 + row) * 3072 + 2560 + kv * HD_ + d0 + c8];
    for (int j = 0; j < 8; ++j) tile[row][c8 + j] = (float)v[j];
  }
  __syncthreads();
  for (int i = 0; i < 2; ++i) {
    int drow = i * 32 + (threadIdx.x >> 3);
    int tc8 = (threadIdx.x & 7) * 8;
    bf16x8 o;
    for (int j = 0; j < 8; ++j) o[j] = (bf16)tile[tc8 + j][drow];
    *(bf16x8*)&Vt[((b * NKV_ + kv) * (long)HD_ + d0 + drow) * T_ + t0 + tc8] = o;
  }
}

// ---------------- causal GQA flash attention (swapped QK^T, per-lane softmax) ----
// Round 3: load-balance restructure. 4 waves / 64 q-rows per block, grid
// (32, NH, B) = 1024 blocks, longest-first (qt reversed). LDS 72KB -> 2
// blocks/CU = 512 resident slots -> 2x oversubscription so the HW queue
// rebalances (round-0's 512-block config was fully resident: a CU's two
// blocks shared the same qt -> 53% balance efficiency, MfmaUtil 13%).
// Softmax reverted to round-0 form (__expf, always-rescale): exp2+defer-max
// measured -6us in round 2.
__global__ __launch_bounds__(256) void flash_attn(const bf16* __restrict__ Q,
                                                  const bf16* __restrict__ K,
                                                  const bf16* __restrict__ V,
                                                  bf16* __restrict__ O) {
  __shared__ bf16 Ks[2][64 * 128];   // [k][d], swizzled
  __shared__ bf16 Vs[2][128 * 64];   // [d][k], swizzled
  __shared__ bf16 Ps[4][16 * 64];    // per-wave P tile [q][k], swizzled
  const int qt = (gridDim.x - 1) - blockIdx.x;  // long blocks first
  const int h = blockIdx.y, b = blockIdx.z;
  const int kv = h >> 2;
  const int tid = threadIdx.x, wid = tid >> 6, lane = tid & 63;
  const int g = lane >> 4, r = lane & 15;
  const int q0 = qt * 64;
  const int qbase = q0 + wid * 16;      // wave-uniform
  const int q = qbase + r;              // this lane's q-row (softmax ownership)

  bf16x8 aq[4];
  const bf16* qp = Q + ((long)(b * T_ + q)) * (NH_ * HD_) + h * HD_;
  for (int kk = 0; kk < 4; ++kk) aq[kk] = *(const bf16x8*)(qp + kk * 32 + g * 8);

  f32x4 oacc[8] = {};
  float m_run = -1e30f, l_run = 0.f;

  const bf16* Kbase = K + ((long)(b * NKV_ + kv)) * T_ * HD_;
  const bf16* Vbase = V + ((long)(b * NKV_ + kv)) * (long)HD_ * T_;
  const int nkt = qt + 1;  // causal: k-tiles of 64 covering [0, q0+64)

  // stage K (16 chunks of 1KB) + V^T (16 chunks): 4+4 chunks per wave
  auto stageKV = [&](int buf, int k0) {
    for (int c = 0; c < 4; ++c) {
      int ch = wid * 4 + c;
      {
        int row = ch * 4 + (lane >> 4);
        int srccol = ((lane & 15) ^ (row & 7)) * 8;
        gld_lds16(&Ks[buf][ch * 512], Kbase + (long)(k0 + row) * HD_ + srccol);
      }
      {
        int row = ch * 8 + (lane >> 3);
        int srccol = ((lane & 7) ^ (row & 7)) * 8;
        gld_lds16(&Vs[buf][ch * 512], Vbase + (long)row * T_ + k0 + srccol);
      }
    }
  };

  stageKV(0, 0);
  for (int kt = 0; kt < nkt; ++kt) {
    const int k0 = kt * 64;
    const int cur = kt & 1;
    if (kt + 1 < nkt) {
      stageKV(cur ^ 1, k0 + 64);
      asm volatile("s_waitcnt vmcnt(8)" ::: "memory");  // drain current tile only
    } else {
      asm volatile("s_waitcnt vmcnt(0)" ::: "memory");
    }
    __builtin_amdgcn_s_barrier();

    // S^T = K * Q^T : lane (g,r) holds S[k=k0+n*16+g*4+e][q]
    f32x4 s[4] = {};
    __builtin_amdgcn_s_setprio(1);
    for (int n = 0; n < 4; ++n)
      for (int kk = 0; kk < 4; ++kk) {
        int row = n * 16 + r;
        bf16x8 bk = *(const bf16x8*)(&Ks[cur][row * 128 + (((kk * 4 + g) ^ (row & 7)) * 8)]);
        s[n] = __builtin_amdgcn_mfma_f32_16x16x32_bf16(bk, aq[kk], s[n], 0, 0, 0);
      }
    __builtin_amdgcn_s_setprio(0);

    // per-lane softmax over 16 k-values
    const float scale = 0.088388347648318447f;  // 1/sqrt(128)
    const bool domask = (k0 + 63 > qbase);      // wave-uniform
    float mx = -1e30f;
    if (domask) {
      for (int n = 0; n < 4; ++n) {
        const int km = k0 + n * 16 + g * 4;
        for (int e = 0; e < 4; ++e) {
          float v = s[n][e] * scale;
          if (km + e > q) v = -1e30f;
          s[n][e] = v;
          mx = fmaxf(mx, v);
        }
      }
    } else {
      for (int n = 0; n < 4; ++n)
        for (int e = 0; e < 4; ++e) {
          float v = s[n][e] * scale;
          s[n][e] = v;
          mx = fmaxf(mx, v);
        }
    }
    mx = fmaxf(mx, __shfl_xor(mx, 16, 64));
    mx = fmaxf(mx, __shfl_xor(mx, 32, 64));
    float mnew = fmaxf(m_run, mx);
    float alpha = __expf(m_run - mnew);
    float ls = 0.f;
    for (int n = 0; n < 4; ++n) {
      bf16x4 pb;
      for (int e = 0; e < 4; ++e) {
        float p = __expf(s[n][e] - mnew);
        ls += p;
        pb[e] = (bf16)p;
      }
      int c = n * 2 + (g >> 1);
      *(bf16x4*)(&Ps[wid][r * 64 + ((c ^ (r & 7)) * 8) + (g & 1) * 4]) = pb;
    }
    ls += __shfl_xor(ls, 16, 64);
    ls += __shfl_xor(ls, 32, 64);
    m_run = mnew;
    l_run = l_run * alpha + ls;

    // broadcast alpha to oacc row layout (row = g*4+e held by lane with r==row)
    float al[4];
    for (int e = 0; e < 4; ++e)
      al[e] = __shfl(alpha, (lane & 48) | (g * 4 + e), 64);
    for (int dt = 0; dt < 8; ++dt)
      for (int e = 0; e < 4; ++e) oacc[dt][e] *= al[e];

    asm volatile("s_waitcnt lgkmcnt(0)" ::: "memory");

    // O += P * V
    __builtin_amdgcn_s_setprio(1);
    for (int kk = 0; kk < 2; ++kk) {
      bf16x8 ap = *(const bf16x8*)(&Ps[wid][r * 64 + (((kk * 4 + g) ^ (r & 7)) * 8)]);
      for (int dt = 0; dt < 8; ++dt) {
        int row = dt * 16 + r;
        bf16x8 bv = *(const bf16x8*)(&Vs[cur][row * 64 + (((kk * 4 + g) ^ (row & 7)) * 8)]);
        oacc[dt] = __builtin_amdgcn_mfma_f32_16x16x32_bf16(ap, bv, oacc[dt], 0, 0, 0);
      }
    }
    __builtin_amdgcn_s_setprio(0);
    __builtin_amdgcn_s_barrier();  // protect buf cur before overwrite at kt+2
  }

  // final: redistribute l to oacc row layout, write O
  float li[4];
  for (int e = 0; e < 4; ++e) {
    float lv = __shfl(l_run, (lane & 48) | (g * 4 + e), 64);
    li[e] = 1.f / lv;
  }
  for (int e = 0; e < 4; ++e) {
    const int grow = q0 + wid * 16 + g * 4 + e;
    bf16* dst = O + ((long)(b * T_ + grow)) * (NH_ * HD_) + h * HD_;
    for (int dt = 0; dt < 8; ++dt)
      dst[dt * 16 + r] = (bf16)(oacc[dt][e] * li[e]);
  }
}

extern "C" void kernel_launch(void* const* d_in, const int* in_sizes, int n_in,
                              void* d_out, int out_size, void* d_ws, size_t ws_size,
                              hipStream_t stream) {
  const float* x  = (const float*)d_in[0];
  const float* wq = (const float*)d_in[1];
  const float* wk = (const float*)d_in[2];
  const float* wv = (const float*)d_in[3];
  const float* wo = (const float*)d_in[4];
  const float* qw = (const float*)d_in[5];
  const float* kw = (const float*)d_in[6];
  float* out = (float*)d_out;

  char* p = (char*)d_ws;
  bf16* xb    = (bf16*)(p);                 // 16 MB  [4096][2048]
  bf16* wqkvb = (bf16*)(p + 16777216);      // 12 MB  [3072][2048] (wq|wk|wv)
  bf16* wob   = (bf16*)(p + 29360128);      //  8 MB  [2048][2048]
  bf16* QKVr  = (bf16*)(p + 37748736);      // 24 MB  [4096][3072]
  bf16* Qb    = (bf16*)(p + 62914560);      // 16 MB  [4096][2048]
  bf16* Kb    = (bf16*)(p + 79691776);      //  4 MB  [B][NKV][T][HD]
  bf16* Vt    = (bf16*)(p + 83886080);      //  4 MB  [B][NKV][HD][T]
  bf16* attb  = (bf16*)(p + 88080384);      // 16 MB  [4096][2048]

  cvt_bf16<<<8192, 256, 0, stream>>>(x,  xb, 2097152);
  cvt_bf16<<<4096, 256, 0, stream>>>(wq, wqkvb,           1048576);
  cvt_bf16<<<1024, 256, 0, stream>>>(wk, wqkvb + 4194304,  262144);
  cvt_bf16<<<1024, 256, 0, stream>>>(wv, wqkvb + 5242880,  262144);
  cvt_bf16<<<4096, 256, 0, stream>>>(wo, wob, 1048576);

  // fused QKV projection: [4096][2048] x [3072][2048]^T -> [4096][3072]
  gemm_bt<bf16><<<dim3(24, 32), 256, 0, stream>>>(xb, wqkvb, QKVr, 4096, 3072, 2048);

  norm_rope<0><<<16384, 256, 0, stream>>>(QKVr, qw, Qb);
  norm_rope<1><<<4096, 256, 0, stream>>>(QKVr, kw, Kb);
  vpack<<<dim3(32, 16), 256, 0, stream>>>(QKVr, Vt);

  flash_attn<<<dim3(32, 16, 2), 256, 0, stream>>>(Qb, Kb, Vt, attb);

  gemm_bt<float><<<dim3(16, 32), 256, 0, stream>>>(attb, wob, out, 4096, 2048, 2048);
}

// Round 4
// 234.170 us; speedup vs baseline: 1.2359x; 1.2359x over previous
//
#include <hip/hip_runtime.h>
#include <hip/hip_bf16.h>

#define B_ 2
#define T_ 2048
#define D_ 2048
#define NH_ 16
#define NKV_ 4
#define HD_ 128

using bf16 = __bf16;
using bf16x8 = __attribute__((ext_vector_type(8))) __bf16;
using bf16x4 = __attribute__((ext_vector_type(4))) __bf16;
using f32x4 = __attribute__((ext_vector_type(4))) float;

__device__ __forceinline__ void gld_lds16(bf16* lds, const bf16* g) {
  __builtin_amdgcn_global_load_lds(
      (const __attribute__((address_space(1))) void*)g,
      (__attribute__((address_space(3))) void*)lds, 16, 0, 0);
}

// ---------------- f32 -> bf16 convert ----------------
__global__ __launch_bounds__(256) void cvt_bf16(const float* __restrict__ in,
                                                bf16* __restrict__ out, int n4) {
  int i = blockIdx.x * 256 + threadIdx.x;
  if (i >= n4) return;
  float4 v = ((const float4*)in)[i];
  bf16x4 o;
  o[0] = (bf16)v.x; o[1] = (bf16)v.y; o[2] = (bf16)v.z; o[3] = (bf16)v.w;
  ((bf16x4*)out)[i] = o;
}

// ---------------- GEMM: C[M,N] = A[M,K] * Bt[N,K]^T ----------------
// 128x128 tile, BK=32, 256 threads (4 waves, 2x2), mfma 16x16x32 bf16.
// XCD-aware bijective block swizzle (grid size must be %8==0 — it is).
template<typename OutT>
__global__ __launch_bounds__(256) void gemm_bt(const bf16* __restrict__ A,
                                               const bf16* __restrict__ Bt,
                                               OutT* __restrict__ C,
                                               int M, int N, int K) {
  __shared__ bf16 As[128 * 32];
  __shared__ bf16 Bs[128 * 32];
  const int tid = threadIdx.x;
  const int wid = tid >> 6;
  const int lane = tid & 63;
  const int g = lane >> 4, r = lane & 15;
  const int wm = wid >> 1, wn = wid & 1;
  const int gx = gridDim.x;
  const int nwg = gx * gridDim.y;
  const int flat = blockIdx.y * gx + blockIdx.x;
  const int swz = (flat & 7) * (nwg >> 3) + (flat >> 3);
  const long bm = (long)(swz / gx) * 128, bn = (long)(swz % gx) * 128;
  f32x4 acc[4][4] = {};

  for (int k0 = 0; k0 < K; k0 += 32) {
    __syncthreads();
    for (int c = 0; c < 2; ++c) {
      int ch = wid * 2 + c;
      int row = ch * 16 + (lane >> 2);
      int col = (lane & 3) * 8;
      gld_lds16(As + ch * 512, A + (bm + row) * K + k0 + col);
      gld_lds16(Bs + ch * 512, Bt + (bn + row) * K + k0 + col);
    }
    asm volatile("s_waitcnt vmcnt(0)" ::: "memory");
    __syncthreads();
    bf16x8 af[4], bfr[4];
    for (int m = 0; m < 4; ++m)
      af[m] = *(const bf16x8*)(As + (wm * 64 + m * 16 + r) * 32 + g * 8);
    for (int n = 0; n < 4; ++n)
      bfr[n] = *(const bf16x8*)(Bs + (wn * 64 + n * 16 + r) * 32 + g * 8);
    for (int m = 0; m < 4; ++m)
      for (int n = 0; n < 4; ++n)
        acc[m][n] = __builtin_amdgcn_mfma_f32_16x16x32_bf16(af[m], bfr[n], acc[m][n], 0, 0, 0);
  }

  for (int m = 0; m < 4; ++m)
    for (int n = 0; n < 4; ++n)
      for (int e = 0; e < 4; ++e) {
        long row = bm + wm * 64 + m * 16 + g * 4 + e;
        long col = bn + wn * 64 + n * 16 + r;
        C[row * N + col] = (OutT)acc[m][n][e];
      }
}

// ---------------- fused RMSNorm + RoPE (reads from fused QKV buffer) ----------------
template<int IS_K>
__global__ __launch_bounds__(256) void norm_rope(const bf16* __restrict__ qkv,
                                                 const float* __restrict__ w,
                                                 bf16* __restrict__ out) {
  const int lane = threadIdx.x & 63;
  const int rloc = threadIdx.x >> 6;
  const int NHH = IS_K ? NKV_ : NH_;
  const int COFF = IS_K ? 2048 : 0;
  const long rid = (long)blockIdx.x * 4 + rloc;
  const int h = (int)(rid % NHH);
  const long bt = rid / NHH;  // b*T + t
  const int t = (int)(bt % T_);
  const bf16* src = qkv + bt * 3072 + COFF + h * HD_;
  float v0 = (float)src[lane];
  float v1 = (float)src[lane + 64];
  float ss = v0 * v0 + v1 * v1;
  for (int o = 1; o < 64; o <<= 1) ss += __shfl_xor(ss, o, 64);
  float inv = rsqrtf(ss * (1.f / HD_) + 1e-6f);
  float n0 = v0 * inv * w[lane];
  float n1 = v1 * inv * w[lane + 64];
  float ang = (float)t * exp2f((float)lane * (-13.287712379549449f / 64.f));
  float sv, cv;
  __sincosf(ang, &sv, &cv);
  float o0 = n0 * cv - n1 * sv;
  float o1 = n1 * cv + n0 * sv;
  bf16* dst;
  if (IS_K) {
    long b = bt / T_;
    dst = out + ((b * NKV_ + h) * (long)T_ + t) * HD_;  // [B][NKV][T][HD]
  } else {
    dst = out + (bt * NH_ + h) * HD_;  // [B*T][NH*HD]
  }
  dst[lane] = (bf16)o0;
  dst[lane + 64] = (bf16)o1;
}

// ---------------- V transpose: QKV[.., 2560+kv*128+d] -> [B][NKV][HD][T] ----------------
__global__ __launch_bounds__(256) void vpack(const bf16* __restrict__ qkv,
                                             bf16* __restrict__ Vt) {
  __shared__ float tile[64][65];
  const int tt = blockIdx.x;
  const int dd = blockIdx.y & 1;
  const int bkv = blockIdx.y >> 1;
  const long b = bkv >> 2;
  const int kv = bkv & 3;
  const int t0 = tt * 64, d0 = dd * 64;
  for (int i = 0; i < 2; ++i) {
    int row = i * 32 + (threadIdx.x >> 3);
    int c8 = (threadIdx.x & 7) * 8;
    bf16x8 v = *(const bf16x8*)&qkv[(b * T_ + t0 + row) * 3072 + 2560 + kv * HD_ + d0 + c8];
    for (int j = 0; j < 8; ++j) tile[row][c8 + j] = (float)v[j];
  }
  __syncthreads();
  for (int i = 0; i < 2; ++i) {
    int drow = i * 32 + (threadIdx.x >> 3);
    int tc8 = (threadIdx.x & 7) * 8;
    bf16x8 o;
    for (int j = 0; j < 8; ++j) o[j] = (bf16)tile[tc8 + j][drow];
    *(bf16x8*)&Vt[((b * NKV_ + kv) * (long)HD_ + d0 + drow) * T_ + t0 + tc8] = o;
  }
}

// ---------------- causal GQA flash attention (swapped QK^T, per-lane softmax) ----
// Round 4: exact round-0 structure (8 waves / 128 q-rows, 80KB LDS, 16
// waves/CU — round-3's 4-wave blocks halved TLP and regressed). Single
// change: anti-correlated qt pairing. With grid (16,16,2) = 512 blocks fully
// resident on 256 CUs, co-resident pair is (i, i+256): same (x,y), opposite
// z. qt = z ? x : 15-x makes each CU's pair work sum to a uniform 34 k-tile
// units (was: both blocks same qt -> CU work 4..64, makespan ~53% eff).
__global__ __launch_bounds__(512) void flash_attn(const bf16* __restrict__ Q,
                                                  const bf16* __restrict__ K,
                                                  const bf16* __restrict__ V,
                                                  bf16* __restrict__ O) {
  __shared__ bf16 Ks[2][64 * 128];   // [k][d], swizzled
  __shared__ bf16 Vs[2][128 * 64];   // [d][k], swizzled
  __shared__ bf16 Ps[8][16 * 64];    // per-wave P tile [q][k], swizzled
  const int h = blockIdx.y, b = blockIdx.z;
  const int qt = b ? blockIdx.x : (gridDim.x - 1) - blockIdx.x;  // pair long+short per CU
  const int kv = h >> 2;
  const int tid = threadIdx.x, wid = tid >> 6, lane = tid & 63;
  const int g = lane >> 4, r = lane & 15;
  const int q0 = qt * 128;
  const int qbase = q0 + wid * 16;      // wave-uniform
  const int q = qbase + r;              // this lane's q-row (softmax ownership)

  bf16x8 aq[4];
  const bf16* qp = Q + ((long)(b * T_ + q)) * (NH_ * HD_) + h * HD_;
  for (int kk = 0; kk < 4; ++kk) aq[kk] = *(const bf16x8*)(qp + kk * 32 + g * 8);

  f32x4 oacc[8] = {};
  float m_run = -1e30f, l_run = 0.f;

  const bf16* Kbase = K + ((long)(b * NKV_ + kv)) * T_ * HD_;
  const bf16* Vbase = V + ((long)(b * NKV_ + kv)) * (long)HD_ * T_;
  const int nkt = 2 * qt + 2;

  // stage K (16 chunks of 1KB) + V^T (16 chunks): 2+2 chunks per wave
  auto stageKV = [&](int buf, int k0) {
    for (int c = 0; c < 2; ++c) {
      int ch = wid * 2 + c;
      {
        int row = ch * 4 + (lane >> 4);
        int srccol = ((lane & 15) ^ (row & 7)) * 8;
        gld_lds16(&Ks[buf][ch * 512], Kbase + (long)(k0 + row) * HD_ + srccol);
      }
      {
        int row = ch * 8 + (lane >> 3);
        int srccol = ((lane & 7) ^ (row & 7)) * 8;
        gld_lds16(&Vs[buf][ch * 512], Vbase + (long)row * T_ + k0 + srccol);
      }
    }
  };

  stageKV(0, 0);
  for (int kt = 0; kt < nkt; ++kt) {
    const int k0 = kt * 64;
    const int cur = kt & 1;
    if (kt + 1 < nkt) {
      stageKV(cur ^ 1, k0 + 64);
      asm volatile("s_waitcnt vmcnt(4)" ::: "memory");  // drain current tile only
    } else {
      asm volatile("s_waitcnt vmcnt(0)" ::: "memory");
    }
    __builtin_amdgcn_s_barrier();

    // S^T = K * Q^T : lane (g,r) holds S[k=k0+n*16+g*4+e][q]
    f32x4 s[4] = {};
    __builtin_amdgcn_s_setprio(1);
    for (int n = 0; n < 4; ++n)
      for (int kk = 0; kk < 4; ++kk) {
        int row = n * 16 + r;
        bf16x8 bk = *(const bf16x8*)(&Ks[cur][row * 128 + (((kk * 4 + g) ^ (row & 7)) * 8)]);
        s[n] = __builtin_amdgcn_mfma_f32_16x16x32_bf16(bk, aq[kk], s[n], 0, 0, 0);
      }
    __builtin_amdgcn_s_setprio(0);

    // per-lane softmax over 16 k-values
    const float scale = 0.088388347648318447f;  // 1/sqrt(128)
    const bool domask = (k0 + 63 > qbase);      // wave-uniform
    float mx = -1e30f;
    if (domask) {
      for (int n = 0; n < 4; ++n) {
        const int km = k0 + n * 16 + g * 4;
        for (int e = 0; e < 4; ++e) {
          float v = s[n][e] * scale;
          if (km + e > q) v = -1e30f;
          s[n][e] = v;
          mx = fmaxf(mx, v);
        }
      }
    } else {
      for (int n = 0; n < 4; ++n)
        for (int e = 0; e < 4; ++e) {
          float v = s[n][e] * scale;
          s[n][e] = v;
          mx = fmaxf(mx, v);
        }
    }
    mx = fmaxf(mx, __shfl_xor(mx, 16, 64));
    mx = fmaxf(mx, __shfl_xor(mx, 32, 64));
    float mnew = fmaxf(m_run, mx);
    float alpha = __expf(m_run - mnew);
    float ls = 0.f;
    for (int n = 0; n < 4; ++n) {
      bf16x4 pb;
      for (int e = 0; e < 4; ++e) {
        float p = __expf(s[n][e] - mnew);
        ls += p;
        pb[e] = (bf16)p;
      }
      int c = n * 2 + (g >> 1);
      *(bf16x4*)(&Ps[wid][r * 64 + ((c ^ (r & 7)) * 8) + (g & 1) * 4]) = pb;
    }
    ls += __shfl_xor(ls, 16, 64);
    ls += __shfl_xor(ls, 32, 64);
    m_run = mnew;
    l_run = l_run * alpha + ls;

    // broadcast alpha to oacc row layout (row = g*4+e held by lane with r==row)
    float al[4];
    for (int e = 0; e < 4; ++e)
      al[e] = __shfl(alpha, (lane & 48) | (g * 4 + e), 64);
    for (int dt = 0; dt < 8; ++dt)
      for (int e = 0; e < 4; ++e) oacc[dt][e] *= al[e];

    asm volatile("s_waitcnt lgkmcnt(0)" ::: "memory");

    // O += P * V
    __builtin_amdgcn_s_setprio(1);
    for (int kk = 0; kk < 2; ++kk) {
      bf16x8 ap = *(const bf16x8*)(&Ps[wid][r * 64 + (((kk * 4 + g) ^ (r & 7)) * 8)]);
      for (int dt = 0; dt < 8; ++dt) {
        int row = dt * 16 + r;
        bf16x8 bv = *(const bf16x8*)(&Vs[cur][row * 64 + (((kk * 4 + g) ^ (row & 7)) * 8)]);
        oacc[dt] = __builtin_amdgcn_mfma_f32_16x16x32_bf16(ap, bv, oacc[dt], 0, 0, 0);
      }
    }
    __builtin_amdgcn_s_setprio(0);
    __builtin_amdgcn_s_barrier();  // protect buf cur before overwrite at kt+2
  }

  // final: redistribute l to oacc row layout, write O
  float li[4];
  for (int e = 0; e < 4; ++e) {
    float lv = __shfl(l_run, (lane & 48) | (g * 4 + e), 64);
    li[e] = 1.f / lv;
  }
  for (int e = 0; e < 4; ++e) {
    const int grow = q0 + wid * 16 + g * 4 + e;
    bf16* dst = O + ((long)(b * T_ + grow)) * (NH_ * HD_) + h * HD_;
    for (int dt = 0; dt < 8; ++dt)
      dst[dt * 16 + r] = (bf16)(oacc[dt][e] * li[e]);
  }
}

extern "C" void kernel_launch(void* const* d_in, const int* in_sizes, int n_in,
                              void* d_out, int out_size, void* d_ws, size_t ws_size,
                              hipStream_t stream) {
  const float* x  = (const float*)d_in[0];
  const float* wq = (const float*)d_in[1];
  const float* wk = (const float*)d_in[2];
  const float* wv = (const float*)d_in[3];
  const float* wo = (const float*)d_in[4];
  const float* qw = (const float*)d_in[5];
  const float* kw = (const float*)d_in[6];
  float* out = (float*)d_out;

  char* p = (char*)d_ws;
  bf16* xb    = (bf16*)(p);                 // 16 MB  [4096][2048]
  bf16* wqkvb = (bf16*)(p + 16777216);      // 12 MB  [3072][2048] (wq|wk|wv)
  bf16* wob   = (bf16*)(p + 29360128);      //  8 MB  [2048][2048]
  bf16* QKVr  = (bf16*)(p + 37748736);      // 24 MB  [4096][3072]
  bf16* Qb    = (bf16*)(p + 62914560);      // 16 MB  [4096][2048]
  bf16* Kb    = (bf16*)(p + 79691776);      //  4 MB  [B][NKV][T][HD]
  bf16* Vt    = (bf16*)(p + 83886080);      //  4 MB  [B][NKV][HD][T]
  bf16* attb  = (bf16*)(p + 88080384);      // 16 MB  [4096][2048]

  cvt_bf16<<<8192, 256, 0, stream>>>(x,  xb, 2097152);
  cvt_bf16<<<4096, 256, 0, stream>>>(wq, wqkvb,           1048576);
  cvt_bf16<<<1024, 256, 0, stream>>>(wk, wqkvb + 4194304,  262144);
  cvt_bf16<<<1024, 256, 0, stream>>>(wv, wqkvb + 5242880,  262144);
  cvt_bf16<<<4096, 256, 0, stream>>>(wo, wob, 1048576);

  // fused QKV projection: [4096][2048] x [3072][2048]^T -> [4096][3072]
  gemm_bt<bf16><<<dim3(24, 32), 256, 0, stream>>>(xb, wqkvb, QKVr, 4096, 3072, 2048);

  norm_rope<0><<<16384, 256, 0, stream>>>(QKVr, qw, Qb);
  norm_rope<1><<<4096, 256, 0, stream>>>(QKVr, kw, Kb);
  vpack<<<dim3(32, 16), 256, 0, stream>>>(QKVr, Vt);

  flash_attn<<<dim3(16, 16, 2), 512, 0, stream>>>(Qb, Kb, Vt, attb);

  gemm_bt<float><<<dim3(16, 32), 256, 0, stream>>>(attb, wob, out, 4096, 2048, 2048);
}

// Round 5
// 218.022 us; speedup vs baseline: 1.3274x; 1.0741x over previous
//
#include <hip/hip_runtime.h>
#include <hip/hip_bf16.h>

#define B_ 2
#define T_ 2048
#define D_ 2048
#define NH_ 16
#define NKV_ 4
#define HD_ 128

using bf16 = __bf16;
using bf16x8 = __attribute__((ext_vector_type(8))) __bf16;
using bf16x4 = __attribute__((ext_vector_type(4))) __bf16;
using f32x4 = __attribute__((ext_vector_type(4))) float;

__device__ __forceinline__ void gld_lds16(bf16* lds, const bf16* g) {
  __builtin_amdgcn_global_load_lds(
      (const __attribute__((address_space(1))) void*)g,
      (__attribute__((address_space(3))) void*)lds, 16, 0, 0);
}

// ---------------- fused f32 -> bf16 convert (all 5 tensors, 1 launch) ---------
// segments (in 256-thread blocks of float4): x 8192 | wq 4096 | wk 1024 | wv 1024 | wo 4096
__global__ __launch_bounds__(256) void cvt_all(const float* __restrict__ x,
                                               const float* __restrict__ wq,
                                               const float* __restrict__ wk,
                                               const float* __restrict__ wv,
                                               const float* __restrict__ wo,
                                               bf16* __restrict__ xb,
                                               bf16* __restrict__ wqkvb,
                                               bf16* __restrict__ wob) {
  const int bid = blockIdx.x;
  const float* src;
  bf16* dst;
  int base;
  if (bid < 8192)       { src = x;  dst = xb;              base = bid; }
  else if (bid < 12288) { src = wq; dst = wqkvb;           base = bid - 8192; }
  else if (bid < 13312) { src = wk; dst = wqkvb + 4194304; base = bid - 12288; }
  else if (bid < 14336) { src = wv; dst = wqkvb + 5242880; base = bid - 13312; }
  else                  { src = wo; dst = wob;             base = bid - 14336; }
  const int i = base * 256 + threadIdx.x;
  float4 v = ((const float4*)src)[i];
  bf16x4 o;
  o[0] = (bf16)v.x; o[1] = (bf16)v.y; o[2] = (bf16)v.z; o[3] = (bf16)v.w;
  ((bf16x4*)dst)[i] = o;
}

// ---------------- GEMM: C[M,N] = A[M,K] * Bt[N,K]^T ----------------
// 128x128 tile, BK=32, 256 threads (4 waves, 2x2), mfma 16x16x32 bf16.
// Round 5: triple-buffered LDS (48KB) + counted vmcnt(4) + raw s_barrier
// (1 per K-step). Stage t+2 after barrier t; its target buf (t-1)%3 was
// last read at iter t-1, whose ds_reads retired before each wave's barrier
// arrival -> safe. vmcnt(4) drains only stage(t), keeps stage(t+1) in
// flight (never drain-0 until the last tile). __syncthreads() would
// re-insert the full vmcnt(0) drain -> use raw s_barrier + asm waits.
// XCD-aware bijective block swizzle (grid size must be %8==0 — it is).
template<typename OutT>
__global__ __launch_bounds__(256) void gemm_bt(const bf16* __restrict__ A,
                                               const bf16* __restrict__ Bt,
                                               OutT* __restrict__ C,
                                               int M, int N, int K) {
  __shared__ bf16 As[3][128 * 32];
  __shared__ bf16 Bs[3][128 * 32];
  const int tid = threadIdx.x;
  const int wid = tid >> 6;
  const int lane = tid & 63;
  const int g = lane >> 4, r = lane & 15;
  const int wm = wid >> 1, wn = wid & 1;
  const int gx = gridDim.x;
  const int nwg = gx * gridDim.y;
  const int flat = blockIdx.y * gx + blockIdx.x;
  const int swz = (flat & 7) * (nwg >> 3) + (flat >> 3);
  const long bm = (long)(swz / gx) * 128, bn = (long)(swz % gx) * 128;
  f32x4 acc[4][4] = {};
  const int NT = K >> 5;

  auto stage = [&](int buf, int k0) {
    for (int c = 0; c < 2; ++c) {
      int ch = wid * 2 + c;
      int row = ch * 16 + (lane >> 2);
      int col = (lane & 3) * 8;
      gld_lds16(&As[buf][ch * 512], A + (bm + row) * K + k0 + col);
      gld_lds16(&Bs[buf][ch * 512], Bt + (bn + row) * K + k0 + col);
    }
  };

  stage(0, 0);
  stage(1, 32);
  for (int t = 0; t < NT; ++t) {
    if (t + 1 < NT)
      asm volatile("s_waitcnt vmcnt(4)" ::: "memory");  // stage(t) done, stage(t+1) in flight
    else
      asm volatile("s_waitcnt vmcnt(0)" ::: "memory");
    __builtin_amdgcn_s_barrier();
    if (t + 2 < NT) stage((t + 2) % 3, (t + 2) * 32);
    const bf16* as = As[t % 3];
    const bf16* bs = Bs[t % 3];
    bf16x8 af[4], bfr[4];
    for (int m = 0; m < 4; ++m)
      af[m] = *(const bf16x8*)(as + (wm * 64 + m * 16 + r) * 32 + g * 8);
    for (int n = 0; n < 4; ++n)
      bfr[n] = *(const bf16x8*)(bs + (wn * 64 + n * 16 + r) * 32 + g * 8);
    for (int m = 0; m < 4; ++m)
      for (int n = 0; n < 4; ++n)
        acc[m][n] = __builtin_amdgcn_mfma_f32_16x16x32_bf16(af[m], bfr[n], acc[m][n], 0, 0, 0);
  }

  for (int m = 0; m < 4; ++m)
    for (int n = 0; n < 4; ++n)
      for (int e = 0; e < 4; ++e) {
        long row = bm + wm * 64 + m * 16 + g * 4 + e;
        long col = bn + wn * 64 + n * 16 + r;
        C[row * N + col] = (OutT)acc[m][n][e];
      }
}

// ---------------- fused RMSNorm + RoPE (reads from fused QKV buffer) ----------------
template<int IS_K>
__global__ __launch_bounds__(256) void norm_rope(const bf16* __restrict__ qkv,
                                                 const float* __restrict__ w,
                                                 bf16* __restrict__ out) {
  const int lane = threadIdx.x & 63;
  const int rloc = threadIdx.x >> 6;
  const int NHH = IS_K ? NKV_ : NH_;
  const int COFF = IS_K ? 2048 : 0;
  const long rid = (long)blockIdx.x * 4 + rloc;
  const int h = (int)(rid % NHH);
  const long bt = rid / NHH;  // b*T + t
  const int t = (int)(bt % T_);
  const bf16* src = qkv + bt * 3072 + COFF + h * HD_;
  float v0 = (float)src[lane];
  float v1 = (float)src[lane + 64];
  float ss = v0 * v0 + v1 * v1;
  for (int o = 1; o < 64; o <<= 1) ss += __shfl_xor(ss, o, 64);
  float inv = rsqrtf(ss * (1.f / HD_) + 1e-6f);
  float n0 = v0 * inv * w[lane];
  float n1 = v1 * inv * w[lane + 64];
  float ang = (float)t * exp2f((float)lane * (-13.287712379549449f / 64.f));
  float sv, cv;
  __sincosf(ang, &sv, &cv);
  float o0 = n0 * cv - n1 * sv;
  float o1 = n1 * cv + n0 * sv;
  bf16* dst;
  if (IS_K) {
    long b = bt / T_;
    dst = out + ((b * NKV_ + h) * (long)T_ + t) * HD_;  // [B][NKV][T][HD]
  } else {
    dst = out + (bt * NH_ + h) * HD_;  // [B*T][NH*HD]
  }
  dst[lane] = (bf16)o0;
  dst[lane + 64] = (bf16)o1;
}

// ---------------- V transpose: QKV[.., 2560+kv*128+d] -> [B][NKV][HD][T] ----------------
__global__ __launch_bounds__(256) void vpack(const bf16* __restrict__ qkv,
                                             bf16* __restrict__ Vt) {
  __shared__ float tile[64][65];
  const int tt = blockIdx.x;
  const int dd = blockIdx.y & 1;
  const int bkv = blockIdx.y >> 1;
  const long b = bkv >> 2;
  const int kv = bkv & 3;
  const int t0 = tt * 64, d0 = dd * 64;
  for (int i = 0; i < 2; ++i) {
    int row = i * 32 + (threadIdx.x >> 3);
    int c8 = (threadIdx.x & 7) * 8;
    bf16x8 v = *(const bf16x8*)&qkv[(b * T_ + t0 + row) * 3072 + 2560 + kv * HD_ + d0 + c8];
    for (int j = 0; j < 8; ++j) tile[row][c8 + j] = (float)v[j];
  }
  __syncthreads();
  for (int i = 0; i < 2; ++i) {
    int drow = i * 32 + (threadIdx.x >> 3);
    int tc8 = (threadIdx.x & 7) * 8;
    bf16x8 o;
    for (int j = 0; j < 8; ++j) o[j] = (bf16)tile[tc8 + j][drow];
    *(bf16x8*)&Vt[((b * NKV_ + kv) * (long)HD_ + d0 + drow) * T_ + t0 + tc8] = o;
  }
}

// ---------------- causal GQA flash attention (swapped QK^T, per-lane softmax) ----
// Round-4 winner, unchanged (control this round). 8 waves / 128 q-rows,
// 80KB LDS, 16 waves/CU. Anti-correlated qt pairing: co-resident pair
// (i, i+256) = same (x,y), opposite z; qt = z ? x : 15-x makes per-CU work
// a uniform 34 k-tile units.
__global__ __launch_bounds__(512) void flash_attn(const bf16* __restrict__ Q,
                                                  const bf16* __restrict__ K,
                                                  const bf16* __restrict__ V,
                                                  bf16* __restrict__ O) {
  __shared__ bf16 Ks[2][64 * 128];   // [k][d], swizzled
  __shared__ bf16 Vs[2][128 * 64];   // [d][k], swizzled
  __shared__ bf16 Ps[8][16 * 64];    // per-wave P tile [q][k], swizzled
  const int h = blockIdx.y, b = blockIdx.z;
  const int qt = b ? blockIdx.x : (gridDim.x - 1) - blockIdx.x;  // pair long+short per CU
  const int kv = h >> 2;
  const int tid = threadIdx.x, wid = tid >> 6, lane = tid & 63;
  const int g = lane >> 4, r = lane & 15;
  const int q0 = qt * 128;
  const int qbase = q0 + wid * 16;      // wave-uniform
  const int q = qbase + r;              // this lane's q-row (softmax ownership)

  bf16x8 aq[4];
  const bf16* qp = Q + ((long)(b * T_ + q)) * (NH_ * HD_) + h * HD_;
  for (int kk = 0; kk < 4; ++kk) aq[kk] = *(const bf16x8*)(qp + kk * 32 + g * 8);

  f32x4 oacc[8] = {};
  float m_run = -1e30f, l_run = 0.f;

  const bf16* Kbase = K + ((long)(b * NKV_ + kv)) * T_ * HD_;
  const bf16* Vbase = V + ((long)(b * NKV_ + kv)) * (long)HD_ * T_;
  const int nkt = 2 * qt + 2;

  // stage K (16 chunks of 1KB) + V^T (16 chunks): 2+2 chunks per wave
  auto stageKV = [&](int buf, int k0) {
    for (int c = 0; c < 2; ++c) {
      int ch = wid * 2 + c;
      {
        int row = ch * 4 + (lane >> 4);
        int srccol = ((lane & 15) ^ (row & 7)) * 8;
        gld_lds16(&Ks[buf][ch * 512], Kbase + (long)(k0 + row) * HD_ + srccol);
      }
      {
        int row = ch * 8 + (lane >> 3);
        int srccol = ((lane & 7) ^ (row & 7)) * 8;
        gld_lds16(&Vs[buf][ch * 512], Vbase + (long)row * T_ + k0 + srccol);
      }
    }
  };

  stageKV(0, 0);
  for (int kt = 0; kt < nkt; ++kt) {
    const int k0 = kt * 64;
    const int cur = kt & 1;
    if (kt + 1 < nkt) {
      stageKV(cur ^ 1, k0 + 64);
      asm volatile("s_waitcnt vmcnt(4)" ::: "memory");  // drain current tile only
    } else {
      asm volatile("s_waitcnt vmcnt(0)" ::: "memory");
    }
    __builtin_amdgcn_s_barrier();

    // S^T = K * Q^T : lane (g,r) holds S[k=k0+n*16+g*4+e][q]
    f32x4 s[4] = {};
    __builtin_amdgcn_s_setprio(1);
    for (int n = 0; n < 4; ++n)
      for (int kk = 0; kk < 4; ++kk) {
        int row = n * 16 + r;
        bf16x8 bk = *(const bf16x8*)(&Ks[cur][row * 128 + (((kk * 4 + g) ^ (row & 7)) * 8)]);
        s[n] = __builtin_amdgcn_mfma_f32_16x16x32_bf16(bk, aq[kk], s[n], 0, 0, 0);
      }
    __builtin_amdgcn_s_setprio(0);

    // per-lane softmax over 16 k-values
    const float scale = 0.088388347648318447f;  // 1/sqrt(128)
    const bool domask = (k0 + 63 > qbase);      // wave-uniform
    float mx = -1e30f;
    if (domask) {
      for (int n = 0; n < 4; ++n) {
        const int km = k0 + n * 16 + g * 4;
        for (int e = 0; e < 4; ++e) {
          float v = s[n][e] * scale;
          if (km + e > q) v = -1e30f;
          s[n][e] = v;
          mx = fmaxf(mx, v);
        }
      }
    } else {
      for (int n = 0; n < 4; ++n)
        for (int e = 0; e < 4; ++e) {
          float v = s[n][e] * scale;
          s[n][e] = v;
          mx = fmaxf(mx, v);
        }
    }
    mx = fmaxf(mx, __shfl_xor(mx, 16, 64));
    mx = fmaxf(mx, __shfl_xor(mx, 32, 64));
    float mnew = fmaxf(m_run, mx);
    float alpha = __expf(m_run - mnew);
    float ls = 0.f;
    for (int n = 0; n < 4; ++n) {
      bf16x4 pb;
      for (int e = 0; e < 4; ++e) {
        float p = __expf(s[n][e] - mnew);
        ls += p;
        pb[e] = (bf16)p;
      }
      int c = n * 2 + (g >> 1);
      *(bf16x4*)(&Ps[wid][r * 64 + ((c ^ (r & 7)) * 8) + (g & 1) * 4]) = pb;
    }
    ls += __shfl_xor(ls, 16, 64);
    ls += __shfl_xor(ls, 32, 64);
    m_run = mnew;
    l_run = l_run * alpha + ls;

    // broadcast alpha to oacc row layout (row = g*4+e held by lane with r==row)
    float al[4];
    for (int e = 0; e < 4; ++e)
      al[e] = __shfl(alpha, (lane & 48) | (g * 4 + e), 64);
    for (int dt = 0; dt < 8; ++dt)
      for (int e = 0; e < 4; ++e) oacc[dt][e] *= al[e];

    asm volatile("s_waitcnt lgkmcnt(0)" ::: "memory");

    // O += P * V
    __builtin_amdgcn_s_setprio(1);
    for (int kk = 0; kk < 2; ++kk) {
      bf16x8 ap = *(const bf16x8*)(&Ps[wid][r * 64 + (((kk * 4 + g) ^ (r & 7)) * 8)]);
      for (int dt = 0; dt < 8; ++dt) {
        int row = dt * 16 + r;
        bf16x8 bv = *(const bf16x8*)(&Vs[cur][row * 64 + (((kk * 4 + g) ^ (row & 7)) * 8)]);
        oacc[dt] = __builtin_amdgcn_mfma_f32_16x16x32_bf16(ap, bv, oacc[dt], 0, 0, 0);
      }
    }
    __builtin_amdgcn_s_setprio(0);
    __builtin_amdgcn_s_barrier();  // protect buf cur before overwrite at kt+2
  }

  // final: redistribute l to oacc row layout, write O
  float li[4];
  for (int e = 0; e < 4; ++e) {
    float lv = __shfl(l_run, (lane & 48) | (g * 4 + e), 64);
    li[e] = 1.f / lv;
  }
  for (int e = 0; e < 4; ++e) {
    const int grow = q0 + wid * 16 + g * 4 + e;
    bf16* dst = O + ((long)(b * T_ + grow)) * (NH_ * HD_) + h * HD_;
    for (int dt = 0; dt < 8; ++dt)
      dst[dt * 16 + r] = (bf16)(oacc[dt][e] * li[e]);
  }
}

extern "C" void kernel_launch(void* const* d_in, const int* in_sizes, int n_in,
                              void* d_out, int out_size, void* d_ws, size_t ws_size,
                              hipStream_t stream) {
  const float* x  = (const float*)d_in[0];
  const float* wq = (const float*)d_in[1];
  const float* wk = (const float*)d_in[2];
  const float* wv = (const float*)d_in[3];
  const float* wo = (const float*)d_in[4];
  const float* qw = (const float*)d_in[5];
  const float* kw = (const float*)d_in[6];
  float* out = (float*)d_out;

  char* p = (char*)d_ws;
  bf16* xb    = (bf16*)(p);                 // 16 MB  [4096][2048]
  bf16* wqkvb = (bf16*)(p + 16777216);      // 12 MB  [3072][2048] (wq|wk|wv)
  bf16* wob   = (bf16*)(p + 29360128);      //  8 MB  [2048][2048]
  bf16* QKVr  = (bf16*)(p + 37748736);      // 24 MB  [4096][3072]
  bf16* Qb    = (bf16*)(p + 62914560);      // 16 MB  [4096][2048]
  bf16* Kb    = (bf16*)(p + 79691776);      //  4 MB  [B][NKV][T][HD]
  bf16* Vt    = (bf16*)(p + 83886080);      //  4 MB  [B][NKV][HD][T]
  bf16* attb  = (bf16*)(p + 88080384);      // 16 MB  [4096][2048]

  cvt_all<<<18432, 256, 0, stream>>>(x, wq, wk, wv, wo, xb, wqkvb, wob);

  // fused QKV projection: [4096][2048] x [3072][2048]^T -> [4096][3072]
  gemm_bt<bf16><<<dim3(24, 32), 256, 0, stream>>>(xb, wqkvb, QKVr, 4096, 3072, 2048);

  norm_rope<0><<<16384, 256, 0, stream>>>(QKVr, qw, Qb);
  norm_rope<1><<<4096, 256, 0, stream>>>(QKVr, kw, Kb);
  vpack<<<dim3(32, 16), 256, 0, stream>>>(QKVr, Vt);

  flash_attn<<<dim3(16, 16, 2), 512, 0, stream>>>(Qb, Kb, Vt, attb);

  gemm_bt<float><<<dim3(16, 32), 256, 0, stream>>>(attb, wob, out, 4096, 2048, 2048);
}